// Round 9
// baseline (259.004 us; speedup 1.0000x reference)
//
#include <hip/hip_runtime.h>
#include <math.h>

#define BATCH 16
#define NCLS 80
#define TOPK 100
#define NBOX 22743
#define NSLOT (NCLS*TOPK)   // 8000 per image
#define TPAD 22752          // padded (s,a)-major total per image
#define CAP 1024
#define NSEG 18
#define MAXE 1444           // max elements per (class,segment)
#define QMAX 5776           // max queue entries per block (4 classes * MAXE)
#define NZERO (BATCH*NCLS*256 + BATCH*NCLS)   // ghist + gcnt words

__device__ __forceinline__ float sigf(float x){ return 1.0f/(1.0f + expf(-x)); }

#define BIN_OF(sc) ({ int _b = (int)(__float_as_uint(sc)>>16) - 0x3E99; _b < 0 ? 0 : (_b > 255 ? 255 : _b); })

// segment: one (scale,anchor[,chunk]) row slice; all fields block-uniform
struct Seg { const float* fbase; int a; int P; int qc; int confb; int nb; int lqoff; int tailq; };
__device__ __forceinline__ Seg segdec(int z, const float* f0, const float* f1, const float* f2){
    Seg s;
    if (z < 3){       s.a=z;   s.P=361;  s.qc=91;  s.confb=z*364;                s.nb=z;        s.fbase=f0; s.lqoff=0;      s.tailq=90; }
    else if (z < 6){  int a=z-3; s.a=a;  s.P=1444; s.qc=361; s.confb=1092+a*1444; s.nb=1083+a;  s.fbase=f1; s.lqoff=0;      s.tailq=-1; }
    else { int t=z-6; int a=t>>2, ch=t&3; s.a=a; s.P=5776; s.qc=361;
           s.confb=5424+a*5776+ch*1444;  s.nb=5415+a;  s.fbase=f2; s.lqoff=ch*361; s.tailq=-1; }
    return s;
}

// --- decode: boxes + conf + reject-logit (padded (s,a)-major); zeroes ghist+gcnt
__global__ __launch_bounds__(256)
void decode_kernel(const float* __restrict__ f0, const float* __restrict__ f1,
                   const float* __restrict__ f2, const float* __restrict__ anchors,
                   const float* __restrict__ ishape,
                   float* __restrict__ boxes, float* __restrict__ conf2,
                   float* __restrict__ tlog2, unsigned int* __restrict__ gzero)
{
    int tid = threadIdx.x;
    int b = blockIdx.y;
    int r = blockIdx.x*blockDim.x + tid;
    int gid = (b*gridDim.x + blockIdx.x)*256 + tid;
    if (gid < NZERO) gzero[gid] = 0u;
    if (r >= TPAD) return;
    int sa, p;
    if (r < 1092){ sa = r/364; p = r - sa*364; }
    else if (r < 5424){ int q = r-1092; sa = 3 + q/1444; p = q - (sa-3)*1444; }
    else { int q = r-5424; sa = 6 + q/5776; p = q - (sa-6)*5776; }
    int s = (sa>=6)?2:((sa>=3)?1:0);
    int a = sa - 3*s;
    const float* f; int P, G, off, abase;
    if (s==0){ f=f0; P=361;  G=19; off=0;    abase=6; }
    else if (s==1){ f=f1; P=1444; G=38; off=1083; abase=3; }
    else        { f=f2; P=5776; G=76; off=5415; abase=0; }
    size_t cidx = (size_t)b*TPAD + r;
    if (p >= P){ conf2[cidx] = 0.0f; tlog2[cidx] = INFINITY; return; }

    const float* fb = f + ((size_t)b*255 + a*85)*(size_t)P;
    float tx = fb[(size_t)0*P + p];
    float ty = fb[(size_t)1*P + p];
    float tw = fb[(size_t)2*P + p];
    float th = fb[(size_t)3*P + p];
    float tc = fb[(size_t)4*P + p];
    int yy = p / G, xx = p - yy*G;
    float g = (float)G;
    float aw = anchors[(abase+a)*2+0];
    float ah = anchors[(abase+a)*2+1];
    float xn = (sigf(tx) + (float)xx) / g;
    float yn = (sigf(ty) + (float)yy) / g;
    float wn = aw * expf(tw) / 608.0f;
    float hn = ah * expf(th) / 608.0f;
    float ih = ishape[0], iw = ishape[1];
    float m  = fminf(608.0f/ih, 608.0f/iw);
    float nh = rintf(ih*m), nw = rintf(iw*m);
    float offy = (608.0f - nh) / 2.0f / 608.0f;
    float offx = (608.0f - nw) / 2.0f / 608.0f;
    float scy = 608.0f/nh, scx = 608.0f/nw;
    float y = (yn - offy)*scy;
    float x = (xn - offx)*scx;
    float hh = hn*scy, ww = wn*scx;
    int n = off + p*3 + a;
    size_t o = ((size_t)b*NBOX + n)*4;
    boxes[o+0] = (y - hh/2.0f)*ih;
    boxes[o+1] = (x - ww/2.0f)*iw;
    boxes[o+2] = (y + hh/2.0f)*ih;
    boxes[o+3] = (x + ww/2.0f)*iw;

    float cf = sigf(tc);
    conf2[cidx] = cf;
    float t;
    if (cf > 0.2951f){ float xr = 0.295f/cf; t = logf(xr/(1.0f - xr)); }
    else t = INFINITY;
    tlog2[cidx] = t;   // pv > t  is a strict superset of  cf*sigf(pv) > 0.3
}

// --- scanq: compare (pv>tlog, ballot-compact to LDS queue) + dense exact score.
// PASS 0: per-class histograms. PASS 1: emit candidates with bin >= Tb.
template<int PASS>
__global__ __launch_bounds__(256)
void scanq_kernel(const float* __restrict__ f0, const float* __restrict__ f1,
                  const float* __restrict__ f2, const float* __restrict__ conf2,
                  const float* __restrict__ tlog2,
                  unsigned int* __restrict__ ghist, const int* __restrict__ tb,
                  int* __restrict__ gcnt, float* __restrict__ gsc, int* __restrict__ gix)
{
    int cg = blockIdx.x, b = blockIdx.y, z = blockIdx.z, tid = threadIdx.x;
    int c0 = cg*4, bc0 = b*NCLS + c0;
    __shared__ __align__(16) float cfl[MAXE];
    __shared__ __align__(16) float tll[MAXE];
    __shared__ float pvq[QMAX];
    __shared__ unsigned short mq[QMAX];
    __shared__ unsigned int h[4][256];
    __shared__ int qcnt;
    if (PASS == 0){ h[0][tid]=0; h[1][tid]=0; h[2][tid]=0; h[3][tid]=0; }
    if (tid == 0) qcnt = 0;
    Seg sg = segdec(z, f0, f1, f2);
    const int P = sg.P, qc = sg.qc;
    const int V = (sg.tailq >= 0) ? 361 : qc*4;   // valid elements in segment
    {
        const float* cfp = conf2 + (size_t)b*TPAD + sg.confb;
        const float* tlp = tlog2 + (size_t)b*TPAD + sg.confb;
        for (int q = tid; q < qc; q += 256){
            *(float4*)(cfl + q*4) = *(const float4*)(cfp + q*4);
            *(float4*)(tll + q*4) = *(const float4*)(tlp + q*4);
        }
    }
    __syncthreads();
    const float* prb = sg.fbase + ((size_t)b*255 + sg.a*85 + 5 + c0)*(size_t)P + sg.lqoff*4;
    int lane = tid & 63;
    unsigned long long below = (1ull << lane) - 1ull;

    // compare phase: 2 quads per thread x 4 classes, warp-aggregated queue push
    for (int half = 0; half < 2; half++){
        int lq = tid + half*256;
        bool v = lq < qc;
        int alq = v ? lq : 0;
        float4 tl4 = *(float4*)(tll + alq*4);
        int e0 = alq*4;
#pragma unroll
        for (int cls = 0; cls < 4; cls++){
            float4 pv4 = *(const float4*)(prb + (size_t)cls*P + alq*4);
#pragma unroll
            for (int j = 0; j < 4; j++){
                float pv = (j==0)?pv4.x:((j==1)?pv4.y:((j==2)?pv4.z:pv4.w));
                float tl = (j==0)?tl4.x:((j==1)?tl4.y:((j==2)?tl4.z:tl4.w));
                bool pass = v && (e0 + j < V) && (pv > tl);
                unsigned long long mball = __ballot(pass);
                if (mball){
                    int cnt = __popcll(mball);
                    int leader = __ffsll((unsigned long long)mball) - 1;
                    int base = 0;
                    if (lane == leader) base = atomicAdd(&qcnt, cnt);
                    base = __shfl(base, leader);
                    if (pass){
                        int off = __popcll(mball & below);
                        pvq[base+off] = pv;
                        mq[base+off] = (unsigned short)((cls << 12) | (e0 + j));
                    }
                }
            }
        }
    }
    __syncthreads();
    int n = qcnt;

    if (PASS == 0){
        for (int i = tid; i < n; i += 256){
            unsigned short me = mq[i];
            int cls = me >> 12, e = me & 0xFFF;
            float sc = cfl[e] * sigf(pvq[i]);
            if (sc > 0.3f) atomicAdd(&h[cls][BIN_OF(sc)], 1u);
        }
        __syncthreads();
        size_t hb = ((size_t)bc0)*256 + tid;
        if (h[0][tid]) atomicAdd(&ghist[hb      ], h[0][tid]);
        if (h[1][tid]) atomicAdd(&ghist[hb + 256], h[1][tid]);
        if (h[2][tid]) atomicAdd(&ghist[hb + 512], h[2][tid]);
        if (h[3][tid]) atomicAdd(&ghist[hb + 768], h[3][tid]);
    } else {
        int t0 = tb[bc0], t1 = tb[bc0+1], t2 = tb[bc0+2], t3 = tb[bc0+3];
        for (int i = tid; i < n; i += 256){
            unsigned short me = mq[i];
            int cls = me >> 12, e = me & 0xFFF;
            float sc = cfl[e] * sigf(pvq[i]);
            if (sc > 0.3f){
                int bin = BIN_OF(sc);
                int tX = (cls==0)?t0:((cls==1)?t1:((cls==2)?t2:t3));
                if (bin >= tX){
                    int p = sg.lqoff*4 + e;
                    int pos = atomicAdd(&gcnt[bc0+cls], 1);
                    if (pos < CAP){
                        gsc[(size_t)(bc0+cls)*CAP + pos] = sc;
                        gix[(size_t)(bc0+cls)*CAP + pos] = sg.nb + 3*p;
                    }
                }
            }
        }
    }
}

// ---------------- threshold-bin per (b,c) ----------------
__global__ __launch_bounds__(256)
void tb_kernel(const unsigned int* __restrict__ ghist, int* __restrict__ tb)
{
    int bc = blockIdx.x, tid = threadIdx.x;
    __shared__ int sufA[256], sufB[256];
    __shared__ int TbS;
    if (tid == 0) TbS = 0;
    sufA[tid] = (int)ghist[(size_t)bc*256 + tid];
    __syncthreads();
    int* cur = sufA; int* nxt = sufB;
    for (int d=1; d<256; d<<=1){
        int v = cur[tid] + ((tid+d) < 256 ? cur[tid+d] : 0);
        nxt[tid] = v;
        __syncthreads();
        int* t_ = cur; cur = nxt; nxt = t_;
    }
    if (cur[tid] >= TOPK && (tid == 255 || cur[tid+1] < TOPK)) TbS = tid;
    __syncthreads();
    if (tid == 0) tb[bc] = TbS;
}

// ---------------- per-(b,c): sort candidates + NMS + write out --------------
__global__ __launch_bounds__(256)
void sortnms_kernel(const float* __restrict__ gsc, const int* __restrict__ gix,
                    const int* __restrict__ gcnt, const float* __restrict__ boxes,
                    float* __restrict__ out)
{
    int c = blockIdx.x, b = blockIdx.y, tid = threadIdx.x;
    int bc = b*NCLS + c;
    __shared__ float cs[CAP];
    __shared__ int   ci[CAP];
    int n = gcnt[bc]; if (n > CAP) n = CAP;
    for (int t=tid; t<CAP; t+=256){
        if (t < n){ cs[t] = gsc[(size_t)bc*CAP + t]; ci[t] = gix[(size_t)bc*CAP + t]; }
        else { cs[t] = -INFINITY; ci[t] = 0x7FFFFFFF; }
    }
    __syncthreads();
    int S = 128; while (S < n) S <<= 1;
    for (int k=2; k<=S; k<<=1){
        for (int j=k>>1; j>0; j>>=1){
            for (int t=tid; t<S; t+=256){
                int ixj = t ^ j;
                if (ixj > t){
                    float s1 = cs[t], s2 = cs[ixj];
                    int   i1 = ci[t], i2 = ci[ixj];
                    bool b2_first = (s2 > s1) || (s2 == s1 && i2 < i1);
                    bool b1_first = (s1 > s2) || (s1 == s2 && i1 < i2);
                    bool desc = ((t & k) == 0);
                    bool sw = desc ? b2_first : b1_first;
                    if (sw){ cs[t]=s2; cs[ixj]=s1; ci[t]=i2; ci[ixj]=i1; }
                }
            }
            __syncthreads();
        }
    }

    // NMS on wave 0 (shfl broadcast, no barriers)
    int w = tid >> 6, lane = tid & 63;
    if (w == 0){
        int o0 = bc*TOPK;
        int nn = n < TOPK ? n : TOPK;
        float ay1=0.f,ax1=0.f,ay2=0.f,ax2=0.f,aar=0.f,asc=0.f; int ak=0;
        float by1=0.f,bx1=0.f,by2=0.f,bx2=0.f,bar_=0.f,bsc=0.f; int bk=0;
        {
            float s = cs[lane];
            if (s > 0.3f){
                asc = s;
                size_t q = ((size_t)b*NBOX + ci[lane])*4;
                ay1=boxes[q]; ax1=boxes[q+1]; ay2=boxes[q+2]; ax2=boxes[q+3]; ak=1;
            }
            aar = (ay2-ay1)*(ax2-ax1);
        }
        if (lane + 64 < TOPK){
            float s = cs[lane+64];
            if (s > 0.3f){
                bsc = s;
                size_t q = ((size_t)b*NBOX + ci[lane+64])*4;
                by1=boxes[q]; bx1=boxes[q+1]; by2=boxes[q+2]; bx2=boxes[q+3]; bk=1;
            }
            bar_ = (by2-by1)*(bx2-bx1);
        }
        for (int i=0; i<nn; i++){
            float iy1,ix1,iy2,ix2,iar; int ik;
            if (i < 64){
                iy1=__shfl(ay1,i); ix1=__shfl(ax1,i); iy2=__shfl(ay2,i); ix2=__shfl(ax2,i);
                iar=__shfl(aar,i); ik=__shfl(ak,i);
            } else {
                int l = i - 64;
                iy1=__shfl(by1,l); ix1=__shfl(bx1,l); iy2=__shfl(by2,l); ix2=__shfl(bx2,l);
                iar=__shfl(bar_,l); ik=__shfl(bk,l);
            }
            if (ik){
                if (ak && lane > i){
                    float q1=fmaxf(iy1,ay1), q2=fmaxf(ix1,ax1);
                    float q3=fminf(iy2,ay2), q4=fminf(ix2,ax2);
                    float inter = fmaxf(q3-q1,0.0f)*fmaxf(q4-q2,0.0f);
                    float iou = inter/(iar + aar - inter + 1e-9f);
                    if (iou > 0.3f) ak = 0;
                }
                if (bk && lane + 64 > i){
                    float q1=fmaxf(iy1,by1), q2=fmaxf(ix1,bx1);
                    float q3=fminf(iy2,by2), q4=fminf(ix2,bx2);
                    float inter = fmaxf(q3-q1,0.0f)*fmaxf(q4-q2,0.0f);
                    float iou = inter/(iar + bar_ - inter + 1e-9f);
                    if (iou > 0.3f) bk = 0;
                }
            }
        }
        {
            float k = ak ? 1.0f : 0.0f;
            size_t o5 = ((size_t)(o0+lane))*5;
            out[o5+0]=ay1*k; out[o5+1]=ax1*k; out[o5+2]=ay2*k; out[o5+3]=ax2*k; out[o5+4]=asc*k;
        }
        if (lane + 64 < TOPK){
            float k = bk ? 1.0f : 0.0f;
            size_t o5 = ((size_t)(o0+lane+64))*5;
            out[o5+0]=by1*k; out[o5+1]=bx1*k; out[o5+2]=by2*k; out[o5+3]=bx2*k; out[o5+4]=bsc*k;
        }
    }
}

// -------- per-image top-50 cap via histogram select (no serial argmax) ------
__global__ __launch_bounds__(1024)
void cap_kernel(float* __restrict__ out)
{
    int b = blockIdx.x, tid = threadIdx.x;
    __shared__ unsigned int h[256];
    __shared__ int sufA[256], sufB[256];
    __shared__ float cs[512];
    __shared__ int   ci[512];
    __shared__ int cnt, T50;
    __shared__ unsigned char msk[NSLOT];
    if (tid < 256) h[tid] = 0;
    if (tid == 0){ cnt = 0; T50 = 0; }
    for (int u=tid; u<NSLOT; u+=1024) msk[u] = 0;
    __syncthreads();

    for (int u=tid; u<NSLOT; u+=1024){
        float v = out[((size_t)b*NSLOT + u)*5 + 4];
        if (v > 0.0f) atomicAdd(&h[BIN_OF(v)], 1u);
    }
    __syncthreads();

    if (tid < 256) sufA[tid] = (int)h[tid];
    __syncthreads();
    int* cur = sufA; int* nxt = sufB;
    for (int d=1; d<256; d<<=1){
        if (tid < 256) nxt[tid] = cur[tid] + ((tid+d) < 256 ? cur[tid+d] : 0);
        __syncthreads();
        int* t_ = cur; cur = nxt; nxt = t_;
    }
    if (tid < 256){
        if (cur[tid] >= 50 && (tid == 255 || cur[tid+1] < 50)) T50 = tid;
    }
    __syncthreads();
    int T = T50;

    for (int u=tid; u<NSLOT; u+=1024){
        float v = out[((size_t)b*NSLOT + u)*5 + 4];
        if (v > 0.0f && BIN_OF(v) >= T){
            int pos = atomicAdd(&cnt, 1);
            if (pos < 512){ cs[pos] = v; ci[pos] = u; }
        }
    }
    __syncthreads();
    int n = cnt; if (n > 512) n = 512;
    for (int t=tid; t<512; t+=1024){
        if (t >= n){ cs[t] = -INFINITY; ci[t] = 0x7FFFFFFF; }
    }
    __syncthreads();

    int S = 64; while (S < n) S <<= 1;
    for (int k=2; k<=S; k<<=1){
        for (int j=k>>1; j>0; j>>=1){
            for (int t=tid; t<S; t+=1024){
                int ixj = t ^ j;
                if (ixj > t){
                    float s1 = cs[t], s2 = cs[ixj];
                    int   i1 = ci[t], i2 = ci[ixj];
                    bool b2_first = (s2 > s1) || (s2 == s1 && i2 < i1);
                    bool b1_first = (s1 > s2) || (s1 == s2 && i1 < i2);
                    bool desc = ((t & k) == 0);
                    bool sw = desc ? b2_first : b1_first;
                    if (sw){ cs[t]=s2; cs[ixj]=s1; ci[t]=i2; ci[ixj]=i1; }
                }
            }
            __syncthreads();
        }
    }

    if (tid < 50 && tid < n) msk[ci[tid]] = 1;
    __syncthreads();

    for (int u=tid; u<NSLOT; u+=1024){
        size_t o5 = ((size_t)b*NSLOT + u)*5;
        float v = out[o5 + 4];
        if (v > 0.0f && !msk[u]){
            out[o5+0]=0.f; out[o5+1]=0.f; out[o5+2]=0.f; out[o5+3]=0.f; out[o5+4]=0.f;
        }
    }
}

extern "C" void kernel_launch(void* const* d_in, const int* in_sizes, int n_in,
                              void* d_out, int out_size, void* d_ws, size_t ws_size,
                              hipStream_t stream)
{
    const float* f0 = (const float*)d_in[0];
    const float* f1 = (const float*)d_in[1];
    const float* f2 = (const float*)d_in[2];
    const float* anchors = (const float*)d_in[3];
    const float* ishape  = (const float*)d_in[4];
    float* out = (float*)d_out;

    float* boxes = (float*)d_ws;                                   // 16*22743*4
    float* conf2 = boxes + (size_t)BATCH*NBOX*4;                   // 16*22752
    float* tlog2 = conf2 + (size_t)BATCH*TPAD;                     // 16*22752
    unsigned int* ghist = (unsigned int*)(tlog2 + (size_t)BATCH*TPAD); // 1280*256
    int* gcnt = (int*)(ghist + (size_t)BATCH*NCLS*256);            // 1280 (contiguous after ghist)
    int* tb   = gcnt + BATCH*NCLS;                                 // 1280
    float* gsc = (float*)(tb + BATCH*NCLS);                        // 1280*1024
    int*   gix = (int*)(gsc + (size_t)BATCH*NCLS*CAP);             // 1280*1024

    dim3 dgrid((TPAD + 255)/256, BATCH);
    decode_kernel<<<dgrid, 256, 0, stream>>>(f0, f1, f2, anchors, ishape,
                                             boxes, conf2, tlog2, ghist);

    dim3 hgrid(NCLS/4, BATCH, NSEG);
    scanq_kernel<0><<<hgrid, 256, 0, stream>>>(f0, f1, f2, conf2, tlog2,
                                               ghist, tb, gcnt, gsc, gix);

    tb_kernel<<<BATCH*NCLS, 256, 0, stream>>>(ghist, tb);

    scanq_kernel<1><<<hgrid, 256, 0, stream>>>(f0, f1, f2, conf2, tlog2,
                                               ghist, tb, gcnt, gsc, gix);

    dim3 sgrid(NCLS, BATCH);
    sortnms_kernel<<<sgrid, 256, 0, stream>>>(gsc, gix, gcnt, boxes, out);

    cap_kernel<<<BATCH, 1024, 0, stream>>>(out);
}

// Round 10
// 145.205 us; speedup vs baseline: 1.7837x; 1.7837x over previous
//
#include <hip/hip_runtime.h>
#include <math.h>

#define BATCH 16
#define NCLS 80
#define TOPK 100
#define NBOX 22743
#define NSLOT (NCLS*TOPK)   // 8000 per image
#define TPAD 22752          // padded (s,a)-major total per image
#define CAP 1024
#define NSEG 18
#define NZERO (BATCH*NCLS*256 + BATCH*NCLS)   // ghist + gcnt words

__device__ __forceinline__ float sigf(float x){ return 1.0f/(1.0f + expf(-x)); }
// fast sigmoid: v_exp_f32 + v_rcp_f32; rel err ~1e-6 << bin width (0.8%)
__device__ __forceinline__ float fsigf(float x){
    return __builtin_amdgcn_rcpf(1.0f + __expf(-x));
}

#define BIN_OF(sc) ({ int _b = (int)(__float_as_uint(sc)>>16) - 0x3E99; _b < 0 ? 0 : (_b > 255 ? 255 : _b); })

// segment: one (scale,anchor[,chunk]) row slice; all fields block-uniform
struct Seg { const float* fbase; int a; int P; int qc; int confb; int nb; int lqoff; int tailq; };
__device__ __forceinline__ Seg segdec(int z, const float* f0, const float* f1, const float* f2){
    Seg s;
    if (z < 3){       s.a=z;   s.P=361;  s.qc=91;  s.confb=z*364;                s.nb=z;        s.fbase=f0; s.lqoff=0;      s.tailq=90; }
    else if (z < 6){  int a=z-3; s.a=a;  s.P=1444; s.qc=361; s.confb=1092+a*1444; s.nb=1083+a;  s.fbase=f1; s.lqoff=0;      s.tailq=-1; }
    else { int t=z-6; int a=t>>2, ch=t&3; s.a=a; s.P=5776; s.qc=361;
           s.confb=5424+a*5776+ch*1444;  s.nb=5415+a;  s.fbase=f2; s.lqoff=ch*361; s.tailq=-1; }
    return s;
}

// ------- decode: boxes + conf (padded (s,a)-major); also zeroes ghist+gcnt ----
__global__ __launch_bounds__(256)
void decode_kernel(const float* __restrict__ f0, const float* __restrict__ f1,
                   const float* __restrict__ f2, const float* __restrict__ anchors,
                   const float* __restrict__ ishape,
                   float* __restrict__ boxes, float* __restrict__ conf2,
                   unsigned int* __restrict__ gzero)
{
    int tid = threadIdx.x;
    int b = blockIdx.y;
    int r = blockIdx.x*blockDim.x + tid;
    int gid = (b*gridDim.x + blockIdx.x)*256 + tid;
    if (gid < NZERO) gzero[gid] = 0u;
    if (r >= TPAD) return;
    int sa, p;
    if (r < 1092){ sa = r/364; p = r - sa*364; }
    else if (r < 5424){ int q = r-1092; sa = 3 + q/1444; p = q - (sa-3)*1444; }
    else { int q = r-5424; sa = 6 + q/5776; p = q - (sa-6)*5776; }
    int s = (sa>=6)?2:((sa>=3)?1:0);
    int a = sa - 3*s;
    const float* f; int P, G, off, abase;
    if (s==0){ f=f0; P=361;  G=19; off=0;    abase=6; }
    else if (s==1){ f=f1; P=1444; G=38; off=1083; abase=3; }
    else        { f=f2; P=5776; G=76; off=5415; abase=0; }
    size_t cidx = (size_t)b*TPAD + r;
    if (p >= P){ conf2[cidx] = 0.0f; return; }

    const float* fb = f + ((size_t)b*255 + a*85)*(size_t)P;
    float tx = fb[(size_t)0*P + p];
    float ty = fb[(size_t)1*P + p];
    float tw = fb[(size_t)2*P + p];
    float th = fb[(size_t)3*P + p];
    float tc = fb[(size_t)4*P + p];
    int yy = p / G, xx = p - yy*G;
    float g = (float)G;
    float aw = anchors[(abase+a)*2+0];
    float ah = anchors[(abase+a)*2+1];
    float xn = (sigf(tx) + (float)xx) / g;
    float yn = (sigf(ty) + (float)yy) / g;
    float wn = aw * expf(tw) / 608.0f;
    float hn = ah * expf(th) / 608.0f;
    float ih = ishape[0], iw = ishape[1];
    float m  = fminf(608.0f/ih, 608.0f/iw);
    float nh = rintf(ih*m), nw = rintf(iw*m);
    float offy = (608.0f - nh) / 2.0f / 608.0f;
    float offx = (608.0f - nw) / 2.0f / 608.0f;
    float scy = 608.0f/nh, scx = 608.0f/nw;
    float y = (yn - offy)*scy;
    float x = (xn - offx)*scx;
    float hh = hn*scy, ww = wn*scx;
    int n = off + p*3 + a;
    size_t o = ((size_t)b*NBOX + n)*4;
    boxes[o+0] = (y - hh/2.0f)*ih;
    boxes[o+1] = (x - ww/2.0f)*iw;
    boxes[o+2] = (y + hh/2.0f)*ih;
    boxes[o+3] = (x + ww/2.0f)*iw;

    conf2[cidx] = sigf(tc);
}

// ------- scan pass: APPROX histogram (+byte-bin cache), 4 classes/block ------
// Fast sigmoid here only; exact scores recomputed at emission. Conservative
// mark threshold 0.2995 and Tb slack (-2) in compact guarantee an exact superset.
template<bool WRITEB>
__global__ __launch_bounds__(256)
void scan_kernel(const float* __restrict__ f0, const float* __restrict__ f1,
                 const float* __restrict__ f2, const float* __restrict__ conf2,
                 unsigned int* __restrict__ ghist, unsigned char* __restrict__ binb)
{
    int cg = blockIdx.x, b = blockIdx.y, z = blockIdx.z, tid = threadIdx.x;
    int c0 = cg*4;
    int bc0 = b*NCLS + c0;
    __shared__ unsigned int h[4][256];
    h[0][tid]=0; h[1][tid]=0; h[2][tid]=0; h[3][tid]=0;
    __syncthreads();
    Seg sg = segdec(z, f0, f1, f2);
    const int P = sg.P, qc = sg.qc;
    const float* cfp = conf2 + (size_t)b*TPAD + sg.confb;
    const float* prb = sg.fbase + ((size_t)b*255 + sg.a*85 + 5 + c0)*(size_t)P + sg.lqoff*4;

    int lqA = tid, lqB = tid + 256;
    bool vA = lqA < qc, vB = lqB < qc;
    float4 cfA, cfB, A0, A1, A2, A3, B0, B1, B2, B3;
    if (vA){
        const float* pA = prb + lqA*4;
        cfA = *(const float4*)(cfp + lqA*4);
        A0 = *(const float4*)pA;         A1 = *(const float4*)(pA + P);
        A2 = *(const float4*)(pA + 2*P); A3 = *(const float4*)(pA + 3*P);
    }
    if (vB){
        const float* pB = prb + lqB*4;
        cfB = *(const float4*)(cfp + lqB*4);
        B0 = *(const float4*)pB;         B1 = *(const float4*)(pB + P);
        B2 = *(const float4*)(pB + 2*P); B3 = *(const float4*)(pB + 3*P);
    }
#define HQUAD(cls, Q, CF, LQ) { \
    float s0 = CF.x*fsigf(Q.x), s1 = CF.y*fsigf(Q.y), s2 = CF.z*fsigf(Q.z), s3 = CF.w*fsigf(Q.w); \
    int b0 = BIN_OF(s0), b1 = BIN_OF(s1), b2 = BIN_OF(s2), b3 = BIN_OF(s3); \
    bool k0 = s0 > 0.2995f, k1 = s1 > 0.2995f, k2 = s2 > 0.2995f, k3 = s3 > 0.2995f; \
    if (k0) atomicAdd(&h[cls][b0], 1u); \
    if (k1) atomicAdd(&h[cls][b1], 1u); \
    if (k2) atomicAdd(&h[cls][b2], 1u); \
    if (k3) atomicAdd(&h[cls][b3], 1u); \
    if (WRITEB){ \
        unsigned ub = (k0 ? (unsigned)(b0+1) : 0u) | ((k1 ? (unsigned)(b1+1) : 0u)<<8) \
                    | ((k2 ? (unsigned)(b2+1) : 0u)<<16) | ((k3 ? (unsigned)(b3+1) : 0u)<<24); \
        *(unsigned*)(binb + (size_t)(bc0+cls)*TPAD + sg.confb + (LQ)*4) = ub; } }
    if (vA){
        if (lqA == sg.tailq){
            A0.y=A0.z=A0.w=-INFINITY; A1.y=A1.z=A1.w=-INFINITY;
            A2.y=A2.z=A2.w=-INFINITY; A3.y=A3.z=A3.w=-INFINITY;
        }
        HQUAD(0, A0, cfA, lqA) HQUAD(1, A1, cfA, lqA) HQUAD(2, A2, cfA, lqA) HQUAD(3, A3, cfA, lqA)
    }
    if (vB){
        HQUAD(0, B0, cfB, lqB) HQUAD(1, B1, cfB, lqB) HQUAD(2, B2, cfB, lqB) HQUAD(3, B3, cfB, lqB)
    }
#undef HQUAD
    __syncthreads();
    size_t hb = ((size_t)bc0)*256 + tid;
    if (h[0][tid]) atomicAdd(&ghist[hb      ], h[0][tid]);
    if (h[1][tid]) atomicAdd(&ghist[hb + 256], h[1][tid]);
    if (h[2][tid]) atomicAdd(&ghist[hb + 512], h[2][tid]);
    if (h[3][tid]) atomicAdd(&ghist[hb + 768], h[3][tid]);
}

// ---------------- threshold-bin per (b,c) ----------------
__global__ __launch_bounds__(256)
void tb_kernel(const unsigned int* __restrict__ ghist, int* __restrict__ tb)
{
    int bc = blockIdx.x, tid = threadIdx.x;
    __shared__ int sufA[256], sufB[256];
    __shared__ int TbS;
    if (tid == 0) TbS = 0;
    sufA[tid] = (int)ghist[(size_t)bc*256 + tid];
    __syncthreads();
    int* cur = sufA; int* nxt = sufB;
    for (int d=1; d<256; d<<=1){
        int v = cur[tid] + ((tid+d) < 256 ? cur[tid+d] : 0);
        nxt[tid] = v;
        __syncthreads();
        int* t_ = cur; cur = nxt; nxt = t_;
    }
    if (cur[tid] >= TOPK && (tid == 255 || cur[tid+1] < TOPK)) TbS = tid;
    __syncthreads();
    if (tid == 0) tb[bc] = TbS;
}

// ------- compact2: scan byte-bin cache (approx bins, slack 2), recompute
//         EXACT score only for survivors ------------------------------------
__global__ __launch_bounds__(256)
void compact2_kernel(const float* __restrict__ f0, const float* __restrict__ f1,
                     const float* __restrict__ f2, const float* __restrict__ conf2,
                     const unsigned char* __restrict__ binb,
                     const int* __restrict__ tb, int* __restrict__ gcnt,
                     float* __restrict__ gsc, int* __restrict__ gix)
{
    int cg = blockIdx.x, b = blockIdx.y, z = blockIdx.z, tid = threadIdx.x;
    int c0 = cg*4;
    int bc0 = b*NCLS + c0;
    int t0 = tb[bc0  ] - 2; t0 = t0 < 0 ? 0 : t0;
    int t1 = tb[bc0+1] - 2; t1 = t1 < 0 ? 0 : t1;
    int t2 = tb[bc0+2] - 2; t2 = t2 < 0 ? 0 : t2;
    int t3 = tb[bc0+3] - 2; t3 = t3 < 0 ? 0 : t3;
    Seg sg = segdec(z, f0, f1, f2);
    const int P = sg.P, qc = sg.qc;
    const unsigned char* bbase = binb + sg.confb;

    int lqA = tid, lqB = tid + 256;
    bool vA = lqA < qc, vB = lqB < qc;
    unsigned uA0=0,uA1=0,uA2=0,uA3=0, uB0=0,uB1=0,uB2=0,uB3=0;
    if (vA){
        const unsigned char* pA = bbase + lqA*4;
        uA0 = *(const unsigned*)(pA + (size_t)(bc0  )*TPAD);
        uA1 = *(const unsigned*)(pA + (size_t)(bc0+1)*TPAD);
        uA2 = *(const unsigned*)(pA + (size_t)(bc0+2)*TPAD);
        uA3 = *(const unsigned*)(pA + (size_t)(bc0+3)*TPAD);
    }
    if (vB){
        const unsigned char* pB = bbase + lqB*4;
        uB0 = *(const unsigned*)(pB + (size_t)(bc0  )*TPAD);
        uB1 = *(const unsigned*)(pB + (size_t)(bc0+1)*TPAD);
        uB2 = *(const unsigned*)(pB + (size_t)(bc0+2)*TPAD);
        uB3 = *(const unsigned*)(pB + (size_t)(bc0+3)*TPAD);
    }
#define CWORD(cls, U, TX, LQ) if (U){ \
    for (int j=0; j<4; j++){ \
        unsigned bj = (U >> (8*j)) & 0xFFu; \
        if (bj && (int)bj - 1 >= (TX)){ \
            int off = sg.confb + (LQ)*4 + j; \
            float cf = conf2[(size_t)b*TPAD + off]; \
            int p = (sg.lqoff + (LQ))*4 + j; \
            float pv = sg.fbase[((size_t)b*255 + sg.a*85 + 5 + c0 + cls)*(size_t)P + p]; \
            float sc = cf * sigf(pv); \
            int pos = atomicAdd(&gcnt[bc0+cls], 1); \
            if (pos < CAP){ \
                gsc[(size_t)(bc0+cls)*CAP + pos] = sc; \
                gix[(size_t)(bc0+cls)*CAP + pos] = sg.nb + 3*p; } } } }
    if (vA){
        CWORD(0, uA0, t0, lqA) CWORD(1, uA1, t1, lqA) CWORD(2, uA2, t2, lqA) CWORD(3, uA3, t3, lqA)
    }
    if (vB){
        CWORD(0, uB0, t0, lqB) CWORD(1, uB1, t1, lqB) CWORD(2, uB2, t2, lqB) CWORD(3, uB3, t3, lqB)
    }
#undef CWORD
}

// ------- fallback compact (full rescan, exact scores, slacked Tb) ------------
__global__ __launch_bounds__(256)
void compact_kernel(const float* __restrict__ f0, const float* __restrict__ f1,
                    const float* __restrict__ f2, const float* __restrict__ conf2,
                    const int* __restrict__ tb, int* __restrict__ gcnt,
                    float* __restrict__ gsc, int* __restrict__ gix)
{
    int cg = blockIdx.x, b = blockIdx.y, z = blockIdx.z, tid = threadIdx.x;
    int c0 = cg*4;
    int bc0 = b*NCLS + c0;
    int t0 = tb[bc0  ] - 2; t0 = t0 < 0 ? 0 : t0;
    int t1 = tb[bc0+1] - 2; t1 = t1 < 0 ? 0 : t1;
    int t2 = tb[bc0+2] - 2; t2 = t2 < 0 ? 0 : t2;
    int t3 = tb[bc0+3] - 2; t3 = t3 < 0 ? 0 : t3;
    Seg sg = segdec(z, f0, f1, f2);
    const int P = sg.P, qc = sg.qc;
    const float* cfp = conf2 + (size_t)b*TPAD + sg.confb;
    const float* prb = sg.fbase + ((size_t)b*255 + sg.a*85 + 5 + c0)*(size_t)P + sg.lqoff*4;

    int lqA = tid, lqB = tid + 256;
    bool vA = lqA < qc, vB = lqB < qc;
    float4 cfA, cfB, A0, A1, A2, A3, B0, B1, B2, B3;
    if (vA){
        const float* pA = prb + lqA*4;
        cfA = *(const float4*)(cfp + lqA*4);
        A0 = *(const float4*)pA;         A1 = *(const float4*)(pA + P);
        A2 = *(const float4*)(pA + 2*P); A3 = *(const float4*)(pA + 3*P);
    }
    if (vB){
        const float* pB = prb + lqB*4;
        cfB = *(const float4*)(cfp + lqB*4);
        B0 = *(const float4*)pB;         B1 = *(const float4*)(pB + P);
        B2 = *(const float4*)(pB + 2*P); B3 = *(const float4*)(pB + 3*P);
    }
#define DOJ(cls, TX, SC, IDX) { \
    if ((SC) > 0.3f){ int bin = BIN_OF(SC); \
        if (bin >= (TX)){ \
            int pos = atomicAdd(&gcnt[bc0+cls], 1); \
            if (pos < CAP){ \
                gsc[(size_t)(bc0+cls)*CAP + pos] = (SC); \
                gix[(size_t)(bc0+cls)*CAP + pos] = (IDX); } } } }
#define CQUAD(cls, Q, CF, TX, PBASE) { \
    float s0 = CF.x*sigf(Q.x), s1 = CF.y*sigf(Q.y), s2 = CF.z*sigf(Q.z), s3 = CF.w*sigf(Q.w); \
    DOJ(cls, TX, s0, sg.nb + 3*((PBASE)+0)) \
    DOJ(cls, TX, s1, sg.nb + 3*((PBASE)+1)) \
    DOJ(cls, TX, s2, sg.nb + 3*((PBASE)+2)) \
    DOJ(cls, TX, s3, sg.nb + 3*((PBASE)+3)) }
    if (vA){
        if (lqA == sg.tailq){
            A0.y=A0.z=A0.w=-INFINITY; A1.y=A1.z=A1.w=-INFINITY;
            A2.y=A2.z=A2.w=-INFINITY; A3.y=A3.z=A3.w=-INFINITY;
        }
        int pbase = (sg.lqoff + lqA)*4;
        CQUAD(0, A0, cfA, t0, pbase) CQUAD(1, A1, cfA, t1, pbase)
        CQUAD(2, A2, cfA, t2, pbase) CQUAD(3, A3, cfA, t3, pbase)
    }
    if (vB){
        int pbase = (sg.lqoff + lqB)*4;
        CQUAD(0, B0, cfB, t0, pbase) CQUAD(1, B1, cfB, t1, pbase)
        CQUAD(2, B2, cfB, t2, pbase) CQUAD(3, B3, cfB, t3, pbase)
    }
#undef CQUAD
#undef DOJ
}

// ---------------- per-(b,c): sort candidates + NMS + write out --------------
__global__ __launch_bounds__(256)
void sortnms_kernel(const float* __restrict__ gsc, const int* __restrict__ gix,
                    const int* __restrict__ gcnt, const float* __restrict__ boxes,
                    float* __restrict__ out)
{
    int c = blockIdx.x, b = blockIdx.y, tid = threadIdx.x;
    int bc = b*NCLS + c;
    __shared__ float cs[CAP];
    __shared__ int   ci[CAP];
    int n = gcnt[bc]; if (n > CAP) n = CAP;
    for (int t=tid; t<CAP; t+=256){
        if (t < n){ cs[t] = gsc[(size_t)bc*CAP + t]; ci[t] = gix[(size_t)bc*CAP + t]; }
        else { cs[t] = -INFINITY; ci[t] = 0x7FFFFFFF; }
    }
    __syncthreads();
    int S = 128; while (S < n) S <<= 1;
    for (int k=2; k<=S; k<<=1){
        for (int j=k>>1; j>0; j>>=1){
            for (int t=tid; t<S; t+=256){
                int ixj = t ^ j;
                if (ixj > t){
                    float s1 = cs[t], s2 = cs[ixj];
                    int   i1 = ci[t], i2 = ci[ixj];
                    bool b2_first = (s2 > s1) || (s2 == s1 && i2 < i1);
                    bool b1_first = (s1 > s2) || (s1 == s2 && i1 < i2);
                    bool desc = ((t & k) == 0);
                    bool sw = desc ? b2_first : b1_first;
                    if (sw){ cs[t]=s2; cs[ixj]=s1; ci[t]=i2; ci[ixj]=i1; }
                }
            }
            __syncthreads();
        }
    }

    // NMS on wave 0 (shfl broadcast, no barriers)
    int w = tid >> 6, lane = tid & 63;
    if (w == 0){
        int o0 = bc*TOPK;
        int nn = n < TOPK ? n : TOPK;
        float ay1=0.f,ax1=0.f,ay2=0.f,ax2=0.f,aar=0.f,asc=0.f; int ak=0;
        float by1=0.f,bx1=0.f,by2=0.f,bx2=0.f,bar_=0.f,bsc=0.f; int bk=0;
        {
            float s = cs[lane];
            if (s > 0.3f){
                asc = s;
                size_t q = ((size_t)b*NBOX + ci[lane])*4;
                ay1=boxes[q]; ax1=boxes[q+1]; ay2=boxes[q+2]; ax2=boxes[q+3]; ak=1;
            }
            aar = (ay2-ay1)*(ax2-ax1);
        }
        if (lane + 64 < TOPK){
            float s = cs[lane+64];
            if (s > 0.3f){
                bsc = s;
                size_t q = ((size_t)b*NBOX + ci[lane+64])*4;
                by1=boxes[q]; bx1=boxes[q+1]; by2=boxes[q+2]; bx2=boxes[q+3]; bk=1;
            }
            bar_ = (by2-by1)*(bx2-bx1);
        }
        for (int i=0; i<nn; i++){
            float iy1,ix1,iy2,ix2,iar; int ik;
            if (i < 64){
                iy1=__shfl(ay1,i); ix1=__shfl(ax1,i); iy2=__shfl(ay2,i); ix2=__shfl(ax2,i);
                iar=__shfl(aar,i); ik=__shfl(ak,i);
            } else {
                int l = i - 64;
                iy1=__shfl(by1,l); ix1=__shfl(bx1,l); iy2=__shfl(by2,l); ix2=__shfl(bx2,l);
                iar=__shfl(bar_,l); ik=__shfl(bk,l);
            }
            if (ik){
                if (ak && lane > i){
                    float q1=fmaxf(iy1,ay1), q2=fmaxf(ix1,ax1);
                    float q3=fminf(iy2,ay2), q4=fminf(ix2,ax2);
                    float inter = fmaxf(q3-q1,0.0f)*fmaxf(q4-q2,0.0f);
                    float iou = inter/(iar + aar - inter + 1e-9f);
                    if (iou > 0.3f) ak = 0;
                }
                if (bk && lane + 64 > i){
                    float q1=fmaxf(iy1,by1), q2=fmaxf(ix1,bx1);
                    float q3=fminf(iy2,by2), q4=fminf(ix2,bx2);
                    float inter = fmaxf(q3-q1,0.0f)*fmaxf(q4-q2,0.0f);
                    float iou = inter/(iar + bar_ - inter + 1e-9f);
                    if (iou > 0.3f) bk = 0;
                }
            }
        }
        {
            float k = ak ? 1.0f : 0.0f;
            size_t o5 = ((size_t)(o0+lane))*5;
            out[o5+0]=ay1*k; out[o5+1]=ax1*k; out[o5+2]=ay2*k; out[o5+3]=ax2*k; out[o5+4]=asc*k;
        }
        if (lane + 64 < TOPK){
            float k = bk ? 1.0f : 0.0f;
            size_t o5 = ((size_t)(o0+lane+64))*5;
            out[o5+0]=by1*k; out[o5+1]=bx1*k; out[o5+2]=by2*k; out[o5+3]=bx2*k; out[o5+4]=bsc*k;
        }
    }
}

// -------- per-image top-50 cap via histogram select (no serial argmax) ------
__global__ __launch_bounds__(1024)
void cap_kernel(float* __restrict__ out)
{
    int b = blockIdx.x, tid = threadIdx.x;
    __shared__ unsigned int h[256];
    __shared__ int sufA[256], sufB[256];
    __shared__ float cs[512];
    __shared__ int   ci[512];
    __shared__ int cnt, T50;
    __shared__ unsigned char msk[NSLOT];
    if (tid < 256) h[tid] = 0;
    if (tid == 0){ cnt = 0; T50 = 0; }
    for (int u=tid; u<NSLOT; u+=1024) msk[u] = 0;
    __syncthreads();

    for (int u=tid; u<NSLOT; u+=1024){
        float v = out[((size_t)b*NSLOT + u)*5 + 4];
        if (v > 0.0f) atomicAdd(&h[BIN_OF(v)], 1u);
    }
    __syncthreads();

    if (tid < 256) sufA[tid] = (int)h[tid];
    __syncthreads();
    int* cur = sufA; int* nxt = sufB;
    for (int d=1; d<256; d<<=1){
        if (tid < 256) nxt[tid] = cur[tid] + ((tid+d) < 256 ? cur[tid+d] : 0);
        __syncthreads();
        int* t_ = cur; cur = nxt; nxt = t_;
    }
    if (tid < 256){
        if (cur[tid] >= 50 && (tid == 255 || cur[tid+1] < 50)) T50 = tid;
    }
    __syncthreads();
    int T = T50;

    for (int u=tid; u<NSLOT; u+=1024){
        float v = out[((size_t)b*NSLOT + u)*5 + 4];
        if (v > 0.0f && BIN_OF(v) >= T){
            int pos = atomicAdd(&cnt, 1);
            if (pos < 512){ cs[pos] = v; ci[pos] = u; }
        }
    }
    __syncthreads();
    int n = cnt; if (n > 512) n = 512;
    for (int t=tid; t<512; t+=1024){
        if (t >= n){ cs[t] = -INFINITY; ci[t] = 0x7FFFFFFF; }
    }
    __syncthreads();

    int S = 64; while (S < n) S <<= 1;
    for (int k=2; k<=S; k<<=1){
        for (int j=k>>1; j>0; j>>=1){
            for (int t=tid; t<S; t+=1024){
                int ixj = t ^ j;
                if (ixj > t){
                    float s1 = cs[t], s2 = cs[ixj];
                    int   i1 = ci[t], i2 = ci[ixj];
                    bool b2_first = (s2 > s1) || (s2 == s1 && i2 < i1);
                    bool b1_first = (s1 > s2) || (s1 == s2 && i1 < i2);
                    bool desc = ((t & k) == 0);
                    bool sw = desc ? b2_first : b1_first;
                    if (sw){ cs[t]=s2; cs[ixj]=s1; ci[t]=i2; ci[ixj]=i1; }
                }
            }
            __syncthreads();
        }
    }

    if (tid < 50 && tid < n) msk[ci[tid]] = 1;
    __syncthreads();

    for (int u=tid; u<NSLOT; u+=1024){
        size_t o5 = ((size_t)b*NSLOT + u)*5;
        float v = out[o5 + 4];
        if (v > 0.0f && !msk[u]){
            out[o5+0]=0.f; out[o5+1]=0.f; out[o5+2]=0.f; out[o5+3]=0.f; out[o5+4]=0.f;
        }
    }
}

extern "C" void kernel_launch(void* const* d_in, const int* in_sizes, int n_in,
                              void* d_out, int out_size, void* d_ws, size_t ws_size,
                              hipStream_t stream)
{
    const float* f0 = (const float*)d_in[0];
    const float* f1 = (const float*)d_in[1];
    const float* f2 = (const float*)d_in[2];
    const float* anchors = (const float*)d_in[3];
    const float* ishape  = (const float*)d_in[4];
    float* out = (float*)d_out;

    float* boxes = (float*)d_ws;                                   // 16*22743*4
    float* conf2 = boxes + (size_t)BATCH*NBOX*4;                   // 16*22752
    unsigned int* ghist = (unsigned int*)(conf2 + (size_t)BATCH*TPAD); // 1280*256
    int* gcnt = (int*)(ghist + (size_t)BATCH*NCLS*256);            // 1280 (contiguous after ghist)
    int* tb   = gcnt + BATCH*NCLS;                                 // 1280
    float* gsc = (float*)(tb + BATCH*NCLS);                        // 1280*1024
    int*   gix = (int*)(gsc + (size_t)BATCH*NCLS*CAP);             // 1280*1024
    unsigned char* binb = (unsigned char*)(gix + (size_t)BATCH*NCLS*CAP); // 16*80*22752 bytes

    size_t words = (size_t)BATCH*NBOX*4 + (size_t)BATCH*TPAD + (size_t)BATCH*NCLS*256
                 + 2*(size_t)BATCH*NCLS + 2*(size_t)BATCH*NCLS*CAP;
    size_t need = words*4 + (size_t)BATCH*NCLS*TPAD;
    bool useB = ws_size >= need;

    dim3 dgrid((TPAD + 255)/256, BATCH);
    decode_kernel<<<dgrid, 256, 0, stream>>>(f0, f1, f2, anchors, ishape,
                                             boxes, conf2, ghist);

    dim3 hgrid(NCLS/4, BATCH, NSEG);
    if (useB)
        scan_kernel<true><<<hgrid, 256, 0, stream>>>(f0, f1, f2, conf2, ghist, binb);
    else
        scan_kernel<false><<<hgrid, 256, 0, stream>>>(f0, f1, f2, conf2, ghist, binb);

    tb_kernel<<<BATCH*NCLS, 256, 0, stream>>>(ghist, tb);

    if (useB)
        compact2_kernel<<<hgrid, 256, 0, stream>>>(f0, f1, f2, conf2, binb, tb, gcnt, gsc, gix);
    else
        compact_kernel<<<hgrid, 256, 0, stream>>>(f0, f1, f2, conf2, tb, gcnt, gsc, gix);

    dim3 sgrid(NCLS, BATCH);
    sortnms_kernel<<<sgrid, 256, 0, stream>>>(gsc, gix, gcnt, boxes, out);

    cap_kernel<<<BATCH, 1024, 0, stream>>>(out);
}